// Round 1
// baseline (288.116 us; speedup 1.0000x reference)
//
#include <hip/hip_runtime.h>
#include <hip/hip_bf16.h>
#include <math.h>

// Problem: SimCLR NT-Xent contrastive loss.
// B=4096, D=256, n=2B=8192, T=0.5.
// z = rownorm(concat(a,b)); sim = z z^T / T in [-2,2];
// denom_i = logsumexp_{j!=i} sim_ij  (use FIXED shift 2: sim <= 2 always)
// pos_i = sim[i, i^4096]; loss = mean(denom - pos).

#define NROWS 8192
#define BHALF 4096
#define DDIM  256
#define JSPLIT 4
#define JCHUNK (NROWS / JSPLIT)

typedef __attribute__((ext_vector_type(8))) __bf16 bf16x8;
typedef __attribute__((ext_vector_type(4))) float f32x4;

// ---------------- Kernel 1: normalize rows -> bf16 z ----------------
// One wave (64 lanes) per row; lane loads float4 (4 elems * 64 = 256).
__global__ __launch_bounds__(256) void norm_kernel(
    const float* __restrict__ a, const float* __restrict__ b,
    __hip_bfloat16* __restrict__ z) {
  int row = blockIdx.x * 4 + (threadIdx.x >> 6);
  int lane = threadIdx.x & 63;
  const float* src = (row < BHALF) ? (a + (size_t)row * DDIM)
                                   : (b + (size_t)(row - BHALF) * DDIM);
  float4 v = ((const float4*)src)[lane];
  float ss = v.x * v.x + v.y * v.y + v.z * v.z + v.w * v.w;
  #pragma unroll
  for (int m = 1; m < 64; m <<= 1) ss += __shfl_xor(ss, m, 64);
  float inv = rsqrtf(ss);
  // one Newton refinement for good measure (cheap, once per element)
  inv = inv * (1.5f - 0.5f * ss * inv * inv);

  union { __hip_bfloat16 h; unsigned short u; } c0, c1, c2, c3;
  c0.h = __float2bfloat16(v.x * inv);
  c1.h = __float2bfloat16(v.y * inv);
  c2.h = __float2bfloat16(v.z * inv);
  c3.h = __float2bfloat16(v.w * inv);
  ushort4 o = make_ushort4(c0.u, c1.u, c2.u, c3.u);
  *(ushort4*)(z + (size_t)row * DDIM + lane * 4) = o;
}

// ---------------- Kernel 2: fused z z^T + exp-sum + pos capture ----------------
// Grid: (128 row-blocks, JSPLIT col-splits), block = 256 threads (4 waves).
// Each wave owns 16 rows; A fragments (full K=256) preloaded in registers.
// Stream j tiles of 16 cols, 2 tiles in flight for MFMA ILP.
__global__ __launch_bounds__(256, 2) void sim_kernel(
    const __hip_bfloat16* __restrict__ z,
    float* __restrict__ s_part, float* __restrict__ pos_part) {
  int rb = blockIdx.x;          // 0..127
  int js = blockIdx.y;          // 0..JSPLIT-1
  int wave = threadIdx.x >> 6;  // 0..3
  int lane = threadIdx.x & 63;
  int lrow = lane & 15;         // fragment row/col index
  int kgrp = lane >> 4;         // 0..3 (k-group of 8)

  int r0 = rb * 64 + wave * 16;   // this wave's 16-row base
  int jbase = js * JCHUNK;

  const bf16x8* zv = (const bf16x8*)z;  // row stride = 256/8 = 32 vectors

  // Preload A fragments: 8 frags cover K=256 (32 per frag).
  bf16x8 afrag[8];
  {
    size_t arow = (size_t)(r0 + lrow) * 32;
    #pragma unroll
    for (int kk = 0; kk < 8; ++kk) afrag[kk] = zv[arow + kk * 4 + kgrp];
  }

  float s_acc[4] = {0.f, 0.f, 0.f, 0.f};
  float pos_acc[4] = {0.f, 0.f, 0.f, 0.f};
  int ptile = r0 ^ BHALF;  // tile base of positive columns for these rows

  // precompute per-lane "am I the (row==col) lane" per reg r
  bool onlane[4];
  #pragma unroll
  for (int r = 0; r < 4; ++r) onlane[r] = (lrow == (kgrp * 4 + r));

  for (int j0 = jbase; j0 < jbase + JCHUNK; j0 += 32) {
    f32x4 c0 = {0.f, 0.f, 0.f, 0.f};
    f32x4 c1 = {0.f, 0.f, 0.f, 0.f};
    size_t brow0 = (size_t)(j0 + lrow) * 32;
    size_t brow1 = (size_t)(j0 + 16 + lrow) * 32;
    #pragma unroll
    for (int kk = 0; kk < 8; ++kk) {
      bf16x8 b0 = zv[brow0 + kk * 4 + kgrp];
      bf16x8 b1 = zv[brow1 + kk * 4 + kgrp];
      c0 = __builtin_amdgcn_mfma_f32_16x16x32_bf16(afrag[kk], b0, c0, 0, 0, 0);
      c1 = __builtin_amdgcn_mfma_f32_16x16x32_bf16(afrag[kk], b1, c1, 0, 0, 0);
    }
    #pragma unroll
    for (int t = 0; t < 2; ++t) {
      int jt = j0 + t * 16;
      bool isdiag = (jt == r0);     // wave-uniform
      bool ispos  = (jt == ptile);  // wave-uniform
      #pragma unroll
      for (int r = 0; r < 4; ++r) {
        float dot = (t == 0) ? c0[r] : c1[r];
        float v = dot + dot;               // sim = dot / 0.5
        float e = __expf(v - 2.0f);        // shift by fixed max bound 2
        if (isdiag && onlane[r]) e = 0.0f; // exclude self-similarity
        if (ispos && onlane[r]) pos_acc[r] = v;
        s_acc[r] += e;
      }
    }
  }

  // Reduce across the 16 column-lanes; lane with lrow==0 owns the row result.
  #pragma unroll
  for (int r = 0; r < 4; ++r) {
    float s = s_acc[r], p = pos_acc[r];
    #pragma unroll
    for (int m = 1; m < 16; m <<= 1) {
      s += __shfl_xor(s, m, 64);
      p += __shfl_xor(p, m, 64);
    }
    if (lrow == 0) {
      int grow = r0 + kgrp * 4 + r;
      s_part[js * NROWS + grow] = s;
      pos_part[js * NROWS + grow] = p;
    }
  }
}

// ---------------- Kernel 3: finalize ----------------
__global__ __launch_bounds__(256) void final_kernel(
    const float* __restrict__ s_part, const float* __restrict__ pos_part,
    float* __restrict__ out) {
  int t = threadIdx.x;
  float acc = 0.f;
  for (int i = t; i < NROWS; i += 256) {
    float s = 0.f, p = 0.f;
    #pragma unroll
    for (int js = 0; js < JSPLIT; ++js) {
      s += s_part[js * NROWS + i];
      p += pos_part[js * NROWS + i];
    }
    acc += (2.0f + logf(s) - p);
  }
  #pragma unroll
  for (int m = 1; m < 64; m <<= 1) acc += __shfl_xor(acc, m, 64);
  __shared__ float red[4];
  if ((t & 63) == 0) red[t >> 6] = acc;
  __syncthreads();
  if (t == 0) out[0] = (red[0] + red[1] + red[2] + red[3]) / (float)NROWS;
}

// ---------------- Launcher ----------------
extern "C" void kernel_launch(void* const* d_in, const int* in_sizes, int n_in,
                              void* d_out, int out_size, void* d_ws, size_t ws_size,
                              hipStream_t stream) {
  const float* a = (const float*)d_in[0];
  const float* b = (const float*)d_in[1];
  float* out = (float*)d_out;
  char* ws = (char*)d_ws;

  __hip_bfloat16* z = (__hip_bfloat16*)ws;                       // 4 MB
  float* s_part = (float*)(ws + (size_t)NROWS * DDIM * 2);       // 128 KB
  float* pos_part = s_part + JSPLIT * NROWS;                     // 128 KB

  hipLaunchKernelGGL(norm_kernel, dim3(NROWS / 4), dim3(256), 0, stream, a, b, z);
  hipLaunchKernelGGL(sim_kernel, dim3(128, JSPLIT), dim3(256), 0, stream,
                     z, s_part, pos_part);
  hipLaunchKernelGGL(final_kernel, dim3(1), dim3(256), 0, stream,
                     s_part, pos_part, out);
}

// Round 3
// 53.002 us; speedup vs baseline: 5.4359x; 5.4359x over previous
//
#include <hip/hip_runtime.h>
#include <hip/hip_bf16.h>
#include <math.h>

// SimCLR NT-Xent: B=4096, D=256, n=8192, T=0.5.
// z = rownorm(concat(a,b)) stored as bf16 in a bank-swizzled layout:
//   stored_byte_in_row = logical_byte ^ ((row&7)<<4)   (16B-granule XOR)
// sim = 2*(z_i . z_j) in [-2,2]; exp(sim-2) = exp2(dot*K1 - K1), K1=2*log2(e).
// S_i = sum_j exp(sim_ij - 2) over ALL j (incl. diag); diag removed in the
// rowterm kernel via selfdot. loss = mean(2 + ln(S_i - exp2(K1*selfdot_i-K1))
//                                         - 2*posdot_i).

#define NROWS 8192
#define BHALF 4096
#define DDIM  256
#define ROWB  512                  // bytes per bf16 row
#define JSPLIT 16
#define JCHUNK (NROWS / JSPLIT)    // 512 cols per block
#define JT 64                      // cols per pipeline step
#define NSTEPS (JCHUNK / JT)       // 8
#define TILEB (JT * ROWB)          // 32 KiB per LDS buffer

#define K1F 2.8853900817779268f    // 2*log2(e)
#define LN2F 0.6931471805599453f

typedef __attribute__((ext_vector_type(8))) __bf16 bf16x8;
typedef __attribute__((ext_vector_type(4))) float f32x4;

#if __has_builtin(__builtin_amdgcn_exp2f)
#define FEXP2(x) __builtin_amdgcn_exp2f(x)
#else
#define FEXP2(x) __exp2f(x)
#endif
#if __has_builtin(__builtin_amdgcn_logf)
#define FLOG2(x) __builtin_amdgcn_logf(x)
#else
#define FLOG2(x) __log2f(x)
#endif

__device__ __forceinline__ float bfu(unsigned short u) {
  union { unsigned v; float f; } x; x.v = ((unsigned)u) << 16; return x.f;
}

// ---------------- Kernel 1: normalize rows -> swizzled bf16 z + selfdot ----
__global__ __launch_bounds__(256) void norm_kernel(
    const float* __restrict__ a, const float* __restrict__ b,
    char* __restrict__ zb, float* __restrict__ selfdot) {
  int row = blockIdx.x * 4 + (threadIdx.x >> 6);
  int lane = threadIdx.x & 63;
  const float* src = (row < BHALF) ? (a + (size_t)row * DDIM)
                                   : (b + (size_t)(row - BHALF) * DDIM);
  float4 v = ((const float4*)src)[lane];
  float ss = v.x * v.x + v.y * v.y + v.z * v.z + v.w * v.w;
  #pragma unroll
  for (int m = 1; m < 64; m <<= 1) ss += __shfl_xor(ss, m, 64);
  float inv = rsqrtf(ss);
  inv = inv * (1.5f - 0.5f * ss * inv * inv);

  union { __hip_bfloat16 h; unsigned short u; } c0, c1, c2, c3;
  c0.h = __float2bfloat16(v.x * inv);
  c1.h = __float2bfloat16(v.y * inv);
  c2.h = __float2bfloat16(v.z * inv);
  c3.h = __float2bfloat16(v.w * inv);
  // self-dot of the bf16-rounded row (matches what MFMA computes on diag)
  float q0 = bfu(c0.u), q1 = bfu(c1.u), q2 = bfu(c2.u), q3 = bfu(c3.u);
  float sq = q0 * q0 + q1 * q1 + q2 * q2 + q3 * q3;
  #pragma unroll
  for (int m = 1; m < 64; m <<= 1) sq += __shfl_xor(sq, m, 64);

  ushort4 o = make_ushort4(c0.u, c1.u, c2.u, c3.u);
  int off = row * ROWB + ((lane * 8) ^ ((row & 7) << 4));
  *(ushort4*)(zb + off) = o;
  if (lane == 0) selfdot[row] = sq;
}

// ---------------- Kernel 2: fused z z^T + exp-sum -------------------------
// Grid (32 row-blocks, JSPLIT col-splits), 256 threads = 4 waves.
// Wave owns 64 rows (A resident in 128 VGPRs over full K=256).
// B tiles (64 cols x 256 k) staged in LDS, double buffered, global_load_lds.
__global__ __launch_bounds__(256, 2) void sim_kernel(
    const char* __restrict__ zb, float* __restrict__ s_part) {
  __shared__ __align__(16) char lds[2 * TILEB];  // 64 KiB
  int wave = threadIdx.x >> 6;
  int lane = threadIdx.x & 63;
  int lrow = lane & 15;
  int kgrp = lane >> 4;
  int sw = (lrow & 7) << 4;
  int r0 = blockIdx.x * 256 + wave * 64;
  int jbase = blockIdx.y * JCHUNK;

  // swizzled within-row byte offsets for the 8 K-chunks (bijective, <512)
  int koff[8];
  #pragma unroll
  for (int kk = 0; kk < 8; ++kk) koff[kk] = (kk * 64 + kgrp * 16) ^ sw;

  // --- preload A fragments (64 rows x K=256) ---
  bf16x8 af[4][8];
  #pragma unroll
  for (int rf = 0; rf < 4; ++rf) {
    const char* rp = zb + (size_t)(r0 + rf * 16 + lrow) * ROWB;
    #pragma unroll
    for (int kk = 0; kk < 8; ++kk)
      af[rf][kk] = *(const bf16x8*)(rp + koff[kk]);
  }

  float sacc[4][4] = {};

  // staging: linear 32KB copy (z is pre-swizzled in global), 8KB per wave
  #define STAGE(buf, j0) do {                                                 \
    const char* g_ = zb + (size_t)(j0) * ROWB + wave * 8192 + lane * 16;      \
    char* l_ = lds + (buf) * TILEB + wave * 8192;                             \
    _Pragma("unroll")                                                         \
    for (int c8 = 0; c8 < 8; ++c8)                                            \
      __builtin_amdgcn_global_load_lds(                                       \
          (const __attribute__((address_space(1))) void*)(g_ + c8 * 1024),    \
          (__attribute__((address_space(3))) void*)(l_ + c8 * 1024),          \
          16, 0, 0);                                                          \
  } while (0)

  STAGE(0, jbase);
  __syncthreads();

  for (int s = 0; s < NSTEPS; ++s) {
    if (s + 1 < NSTEPS) STAGE((s + 1) & 1, jbase + (s + 1) * JT);
    const char* lb = lds + (s & 1) * TILEB;
    #pragma unroll
    for (int ct = 0; ct < 4; ++ct) {
      const char* lbr = lb + ct * 8192 + lrow * ROWB;
      bf16x8 bf[8];
      #pragma unroll
      for (int kk = 0; kk < 8; ++kk)
        bf[kk] = *(const bf16x8*)(lbr + koff[kk]);
      f32x4 c0 = {0.f, 0.f, 0.f, 0.f};
      f32x4 c1 = {0.f, 0.f, 0.f, 0.f};
      f32x4 c2 = {0.f, 0.f, 0.f, 0.f};
      f32x4 c3 = {0.f, 0.f, 0.f, 0.f};
      #pragma unroll
      for (int kk = 0; kk < 8; ++kk) {
        c0 = __builtin_amdgcn_mfma_f32_16x16x32_bf16(af[0][kk], bf[kk], c0, 0, 0, 0);
        c1 = __builtin_amdgcn_mfma_f32_16x16x32_bf16(af[1][kk], bf[kk], c1, 0, 0, 0);
        c2 = __builtin_amdgcn_mfma_f32_16x16x32_bf16(af[2][kk], bf[kk], c2, 0, 0, 0);
        c3 = __builtin_amdgcn_mfma_f32_16x16x32_bf16(af[3][kk], bf[kk], c3, 0, 0, 0);
      }
      #pragma unroll
      for (int r = 0; r < 4; ++r) {
        sacc[0][r] += FEXP2(fmaf(c0[r], K1F, -K1F));
        sacc[1][r] += FEXP2(fmaf(c1[r], K1F, -K1F));
        sacc[2][r] += FEXP2(fmaf(c2[r], K1F, -K1F));
        sacc[3][r] += FEXP2(fmaf(c3[r], K1F, -K1F));
      }
    }
    __syncthreads();
  }
  #undef STAGE

  // reduce across the 16 column-lanes (C layout: col=lane&15, row=kgrp*4+r;
  // a transposed interpretation is harmless: sim is symmetric)
  #pragma unroll
  for (int rf = 0; rf < 4; ++rf) {
    #pragma unroll
    for (int r = 0; r < 4; ++r) {
      float v = sacc[rf][r];
      #pragma unroll
      for (int m = 1; m < 16; m <<= 1) v += __shfl_xor(v, m, 64);
      if (lrow == 0) {
        int grow = r0 + rf * 16 + kgrp * 4 + r;
        s_part[blockIdx.y * NROWS + grow] = v;
      }
    }
  }
}

// ---------------- Kernel 3: per-row term (pos dot + assemble) --------------
__global__ __launch_bounds__(256) void rowterm_kernel(
    const char* __restrict__ zb, const float* __restrict__ s_part,
    const float* __restrict__ selfdot, float* __restrict__ bpart) {
  int wave = threadIdx.x >> 6;
  int lane = threadIdx.x & 63;
  int rbase = blockIdx.x * 64 + wave * 16;
  float wacc = 0.f;
  for (int rr = 0; rr < 16; ++rr) {
    int i = rbase + rr;
    int j = i ^ BHALF;                       // (i+B) mod 2B
    int wo = (lane * 8) ^ ((i & 7) << 4);    // j&7 == i&7 (4096 % 8 == 0)
    ushort4 zi = *(const ushort4*)(zb + (size_t)i * ROWB + wo);
    ushort4 zj = *(const ushort4*)(zb + (size_t)j * ROWB + wo);
    float dot = bfu(zi.x) * bfu(zj.x) + bfu(zi.y) * bfu(zj.y) +
                bfu(zi.z) * bfu(zj.z) + bfu(zi.w) * bfu(zj.w);
    float sp = (lane < JSPLIT) ? s_part[lane * NROWS + i] : 0.f;
    #pragma unroll
    for (int m = 1; m < 64; m <<= 1) {
      dot += __shfl_xor(dot, m, 64);
      sp += __shfl_xor(sp, m, 64);
    }
    float s = sp - FEXP2(fmaf(selfdot[i], K1F, -K1F));  // remove diagonal
    wacc += 2.0f + FLOG2(s) * LN2F - 2.0f * dot;        // denom - pos
  }
  __shared__ float red[4];
  if (lane == 0) red[wave] = wacc;
  __syncthreads();
  if (threadIdx.x == 0)
    bpart[blockIdx.x] = red[0] + red[1] + red[2] + red[3];
}

// ---------------- Kernel 4: final sum --------------------------------------
__global__ __launch_bounds__(128) void final_kernel(
    const float* __restrict__ bpart, float* __restrict__ out) {
  int t = threadIdx.x;  // 128 threads = 2 waves
  float v = bpart[t];
  #pragma unroll
  for (int m = 1; m < 64; m <<= 1) v += __shfl_xor(v, m, 64);
  __shared__ float r2[2];
  if ((t & 63) == 0) r2[t >> 6] = v;
  __syncthreads();
  if (t == 0) out[0] = (r2[0] + r2[1]) / (float)NROWS;
}

// ---------------- Launcher --------------------------------------------------
extern "C" void kernel_launch(void* const* d_in, const int* in_sizes, int n_in,
                              void* d_out, int out_size, void* d_ws, size_t ws_size,
                              hipStream_t stream) {
  const float* a = (const float*)d_in[0];
  const float* b = (const float*)d_in[1];
  float* out = (float*)d_out;
  char* ws = (char*)d_ws;

  char* zb = ws;                                            // 4 MiB
  float* selfdot = (float*)(ws + (size_t)NROWS * ROWB);     // 32 KiB
  float* s_part = selfdot + NROWS;                          // 512 KiB
  float* bpart = s_part + (size_t)JSPLIT * NROWS;           // 512 B

  hipLaunchKernelGGL(norm_kernel, dim3(NROWS / 4), dim3(256), 0, stream,
                     a, b, zb, selfdot);
  hipLaunchKernelGGL(sim_kernel, dim3(NROWS / 256, JSPLIT), dim3(256), 0,
                     stream, zb, s_part);
  hipLaunchKernelGGL(rowterm_kernel, dim3(128), dim3(256), 0, stream,
                     zb, s_part, selfdot, bpart);
  hipLaunchKernelGGL(final_kernel, dim3(1), dim3(128), 0, stream, bpart, out);
}